// Round 4
// baseline (1441.907 us; speedup 1.0000x reference)
//
#include <hip/hip_runtime.h>
#include <hip/hip_bf16.h>

#define GLOBAL_AS __attribute__((address_space(1)))
#define LDS_AS    __attribute__((address_space(3)))

typedef __bf16 bf16_t;
typedef __bf16 bf16x8 __attribute__((ext_vector_type(8)));
typedef __bf16 bf16x4 __attribute__((ext_vector_type(4)));
typedef float  f32x4  __attribute__((ext_vector_type(4)));
typedef _Float16 fp16_t;
typedef _Float16 f16x2v __attribute__((ext_vector_type(2)));

static constexpr int Bb = 256;    // batch
static constexpr int Ss = 14;     // seq
static constexpr int Hh = 1024;   // hidden
static constexpr int Cc = 2513;   // classes
static constexpr int NXc = 3584;  // B*S
static constexpr int Kk = 1024;   // K (== F == H)

__device__ __forceinline__ float sigm(float x)   { return 1.0f / (1.0f + __expf(-x)); }
__device__ __forceinline__ float tanh_f(float x) { return 2.0f / (1.0f + __expf(-2.0f * x)) - 1.0f; }

// h buffer offsets (in 128-col blocks): h[0] zeros span 2; h[k] span min(2k,28)
__device__ __forceinline__ int hoff(int k) {
    if (k <= 0) return 0;
    if (k <= 14) return 2 + k * (k - 1);
    return (k == 15) ? 212 : 240;
}

// ---------------------------------------------------------------------------
// XG input-projection GEMM (unchanged m97-recipe, XCD 2D partition).
// C[8192,3584] = W_ih2 @ x^T + bias -> bf16 XG[n'][col][4gates]
// ---------------------------------------------------------------------------
__global__ __launch_bounds__(256, 2)
void gemm_xg(const bf16_t* __restrict__ A, const bf16_t* __restrict__ Bm,
             int rpg, int cpg, int CG, int CB,
             const float* __restrict__ e_bias,
             bf16_t* __restrict__ xg_bf)
{
    const int lin = blockIdx.x;
    const int xcd = lin & 7;
    const int per = lin >> 3;
    const int rg = xcd / CG, cg = xcd % CG;
    const int rb = rg * rpg + per % rpg;
    const int cb = cg * cpg + per / rpg;
    if (cb >= CB) return;

    __shared__ char smem[32768];
    LDS_AS char* sA = (LDS_AS char*)smem;
    LDS_AS char* sB = sA + 16384;

    const int tid  = threadIdx.x;
    const int lane = tid & 63;
    const int wave = tid >> 6;
    const int row0 = rb * 128;
    const int col0 = cb * 128;
    const int mwb  = (wave >> 1) * 64;
    const int nwb  = (wave & 1) * 64;
    const int quad = lane >> 4;
    const int l15  = lane & 15;

    f32x4 acc[4][4] = {};

    for (int kb = 0; kb < Kk; kb += 64) {
#pragma unroll
        for (int it = 0; it < 4; ++it) {
            int c  = it * 256 + tid;
            int m  = c >> 3;
            int kq = (c & 7) ^ (m & 7);
            const bf16_t* ga = A + (size_t)(row0 + m) * Kk + kb + kq * 8;
            const bf16_t* gb = Bm + (size_t)(col0 + m) * Kk + kb + kq * 8;
            LDS_AS char* la = sA + (size_t)(it * 256 + (tid & 192)) * 16;
            LDS_AS char* lb = sB + (size_t)(it * 256 + (tid & 192)) * 16;
            __builtin_amdgcn_global_load_lds((const GLOBAL_AS void*)ga, (LDS_AS void*)la, 16, 0, 0);
            __builtin_amdgcn_global_load_lds((const GLOBAL_AS void*)gb, (LDS_AS void*)lb, 16, 0, 0);
        }
        __syncthreads();
#pragma unroll
        for (int kt = 0; kt < 2; ++kt) {
            bf16x8 af[4], bfr[4];
            const int kq = kt * 4 + quad;
#pragma unroll
            for (int i = 0; i < 4; ++i) {
                int ml = mwb + i * 16 + l15;
                af[i]  = *(const LDS_AS bf16x8*)(sA + (size_t)(ml * 8 + (kq ^ (ml & 7))) * 16);
                int nl = nwb + i * 16 + l15;
                bfr[i] = *(const LDS_AS bf16x8*)(sB + (size_t)(nl * 8 + (kq ^ (nl & 7))) * 16);
            }
#pragma unroll
            for (int i = 0; i < 4; ++i)
#pragma unroll
                for (int j = 0; j < 4; ++j)
                    acc[i][j] = __builtin_amdgcn_mfma_f32_16x16x32_bf16(af[i], bfr[j], acc[i][j], 0, 0, 0);
        }
        __syncthreads();
    }

#pragma unroll
    for (int im = 0; im < 4; ++im) {
#pragma unroll
        for (int jn = 0; jn < 4; ++jn) {
            const int rr  = row0 + mwb + im * 16 + quad * 4;
            const int col = col0 + nwb + jn * 16 + l15;
            f32x4 v = acc[im][jn];
            const int n = rr >> 2;
            f32x4 bi = *(const f32x4*)(e_bias + n * 4);
            bf16x4 o;
            o[0] = (bf16_t)(v[0] + bi[0]); o[1] = (bf16_t)(v[1] + bi[1]);
            o[2] = (bf16_t)(v[2] + bi[2]); o[3] = (bf16_t)(v[3] + bi[3]);
            *(bf16x4*)(xg_bf + ((size_t)n * NXc + col) * 4) = o;
        }
    }
}

// ---------------------------------------------------------------------------
// Persistent dataflow kernel: 16 recurrent steps + classifier, tile-level
// per-(step,col-block) counter sync. 512 blocks (< residency capacity).
// ---------------------------------------------------------------------------
struct PArgs {
    const bf16_t* w_hhu;
    const bf16_t* w_hhr;
    const bf16_t* xg_u;    // [1024][3584][4] bf16
    const bf16_t* xg_r;
    const bf16_t* wc;      // [2513pad][1024] bf16
    bf16_t*  hbuf;         // 268 col-blocks x 128 cols x 1024 (h[0]=zeros)
    fp16_t*  c0;           // c ping-pong [3584][1024] fp16
    fp16_t*  c1;
    unsigned* cnt;         // [16][28]
    const float* bc;
    float* out;            // [3584][2513] fp32
};

__global__ __launch_bounds__(256, 2)
void lstm_persist(PArgs p)
{
    __shared__ char smem[32768];
    LDS_AS char* sA = (LDS_AS char*)smem;
    LDS_AS char* sB = sA + 16384;

    const int tid  = threadIdx.x;
    const int lane = tid & 63;
    const int wave = tid >> 6;
    const int mwb  = (wave >> 1) * 64;
    const int nwb  = (wave & 1) * 64;
    const int quad = lane >> 4;
    const int l15  = lane & 15;
    const int x    = blockIdx.x & 7;      // xcd heuristic (locality only)
    const int lb   = blockIdx.x >> 3;     // local block 0..63
    const int rbg  = x >> 2;              // row group (rb 16-range)
    const int cmod = x & 3;               // col-block mod-4 class

    // ---------------- recurrent wavefront ----------------
    for (int k = 1; k <= 16; ++k) {
        const int a   = (k - 1 < 14) ? (k - 1) : 14;
        const int U2  = 2 * a;                       // active unroll col-blocks
        const int ncu = (U2 > cmod) ? (((U2 - 1 - cmod) >> 2) + 1) : 0;
        int rollC = -1;
        if (k <= 14) {
            int r0 = 2 * k - 2;
            if ((r0 & 3) == cmod) rollC = r0;
            else if (((r0 + 1) & 3) == cmod) rollC = r0 + 1;
        }
        const int nc = ncu + (rollC >= 0 ? 1 : 0);
        const int T  = nc * 16;

        for (int j = lb; j < T; j += 64) {
            const int  ci   = j >> 4;
            const int  rb   = rbg * 16 + (j & 15);
            const bool roll = (ci >= ncu);
            const int  cb   = roll ? rollC : (cmod + 4 * ci);

            if (k > 1) {
                const int dep = (k - 2) * 28 + (roll ? (cb - 2) : cb);
                if (tid == 0)
                    while (__hip_atomic_load(&p.cnt[dep], __ATOMIC_RELAXED,
                                             __HIP_MEMORY_SCOPE_AGENT) < 32u)
                        __builtin_amdgcn_s_sleep(1);
            }
            __syncthreads();

            const bf16_t* A = (roll ? p.w_hhr : p.w_hhu) + (size_t)rb * (128 * Kk);
            int bcb = roll ? (cb - 2) : cb; if (bcb < 0) bcb = 0;   // k==1 -> zeros
            const bf16_t* Bm = p.hbuf + ((size_t)(hoff(k - 1) + bcb) << 17);

            f32x4 acc[4][4] = {};
            for (int kb = 0; kb < Kk; kb += 64) {
#pragma unroll
                for (int it = 0; it < 4; ++it) {
                    int c  = it * 256 + tid;
                    int m  = c >> 3;
                    int kq = (c & 7) ^ (m & 7);
                    const bf16_t* ga = A  + (size_t)m * Kk + kb + kq * 8;
                    const bf16_t* gb = Bm + (size_t)m * Kk + kb + kq * 8;
                    LDS_AS char* la  = sA + (size_t)(it * 256 + (tid & 192)) * 16;
                    LDS_AS char* lb2 = sB + (size_t)(it * 256 + (tid & 192)) * 16;
                    __builtin_amdgcn_global_load_lds((const GLOBAL_AS void*)ga, (LDS_AS void*)la, 16, 0, 0);
                    __builtin_amdgcn_global_load_lds((const GLOBAL_AS void*)gb, (LDS_AS void*)lb2, 16, 0, 0);
                }
                __syncthreads();
#pragma unroll
                for (int kt = 0; kt < 2; ++kt) {
                    bf16x8 af[4], bfr[4];
                    const int kq = kt * 4 + quad;
#pragma unroll
                    for (int i = 0; i < 4; ++i) {
                        int ml = mwb + i * 16 + l15;
                        af[i]  = *(const LDS_AS bf16x8*)(sA + (size_t)(ml * 8 + (kq ^ (ml & 7))) * 16);
                        int nl = nwb + i * 16 + l15;
                        bfr[i] = *(const LDS_AS bf16x8*)(sB + (size_t)(nl * 8 + (kq ^ (nl & 7))) * 16);
                    }
#pragma unroll
                    for (int i2 = 0; i2 < 4; ++i2)
#pragma unroll
                        for (int j2 = 0; j2 < 4; ++j2)
                            acc[i2][j2] = __builtin_amdgcn_mfma_f32_16x16x32_bf16(af[i2], bfr[j2], acc[i2][j2], 0, 0, 0);
                }
                __syncthreads();
            }

            // ---- fused LSTM-cell epilogue ----
            const bf16_t* xg = roll ? p.xg_r : p.xg_u;
            fp16_t*       cw = (k & 1) ? p.c1 : p.c0;
            const fp16_t* cr = (k & 1) ? p.c0 : p.c1;      // parity k-1
            if (k == 1) cr = (const fp16_t*)p.hbuf;         // zeros
            const int crcol0 = bcb * 128;
            const int cwcol0 = cb * 128;
            bf16_t* hw = p.hbuf + ((size_t)(hoff(k) + cb) << 17);
            const int row0 = rb * 128;
#pragma unroll
            for (int im = 0; im < 4; ++im) {
#pragma unroll
                for (int jn = 0; jn < 4; ++jn) {
                    const int rr = row0 + mwb + im * 16 + quad * 4;
                    const int cl = nwb + jn * 16 + l15;      // tile-local col
                    f32x4 v = acc[im][jn];
                    const int n = rr >> 2;
                    bf16x4 xg4 = *(const bf16x4*)(xg + ((size_t)n * NXc + (cb * 128 + cl)) * 4);
                    float gi = v[0] + (float)xg4[0];
                    float gf = v[1] + (float)xg4[1];
                    float gg = v[2] + (float)xg4[2];
                    float go = v[3] + (float)xg4[3];
                    // old c: device-scope dword (L2-bypass -> always fresh)
                    const unsigned* cp = (const unsigned*)(cr + ((size_t)(crcol0 + cl) << 10) + (n & ~1));
                    unsigned cvb = __hip_atomic_load(cp, __ATOMIC_RELAXED, __HIP_MEMORY_SCOPE_AGENT);
                    f16x2v cc; __builtin_memcpy(&cc, &cvb, 4);
                    float cold = (float)cc[n & 1];
                    float c2 = sigm(gf) * cold + sigm(gi) * tanh_f(gg);
                    float h2 = sigm(go) * tanh_f(c2);
                    cw[((size_t)(cwcol0 + cl) << 10) + n] = (fp16_t)c2;
                    hw[((size_t)cl << 10) + n] = (bf16_t)h2;
                }
            }
            __syncthreads();   // all waves' stores at L2 before release
            if (tid == 0)
                __hip_atomic_fetch_add(&p.cnt[(k - 1) * 28 + cb], 1u,
                                       __ATOMIC_RELEASE, __HIP_MEMORY_SCOPE_AGENT);
        }
    }

    // ---------------- classifier phase ----------------
    if (tid == 0)
        for (int c = 0; c < 28; ++c)
            while (__hip_atomic_load(&p.cnt[15 * 28 + c], __ATOMIC_RELAXED,
                                     __HIP_MEMORY_SCOPE_AGENT) < 32u)
                __builtin_amdgcn_s_sleep(1);
    __syncthreads();

    const bf16_t* hf = p.hbuf + ((size_t)hoff(16) << 17);
    for (int i = blockIdx.x; i < 560; i += 512) {
        const int rb = i / 20, cbn = i % 20;
        const int row0 = rb * 128, col0 = cbn * 128;

        f32x4 acc[4][4] = {};
        for (int kb = 0; kb < Kk; kb += 64) {
#pragma unroll
            for (int it = 0; it < 4; ++it) {
                int c  = it * 256 + tid;
                int m  = c >> 3;
                int kq = (c & 7) ^ (m & 7);
                int row = row0 + m;
                int bb = row / 14;
                int ss = row - bb * 14;
                const bf16_t* ga = hf + (size_t)(ss * 256 + bb) * Kk + kb + kq * 8;
                int nr = col0 + m; if (nr >= Cc) nr = 0;
                const bf16_t* gb = p.wc + (size_t)nr * Kk + kb + kq * 8;
                LDS_AS char* la  = sA + (size_t)(it * 256 + (tid & 192)) * 16;
                LDS_AS char* lb2 = sB + (size_t)(it * 256 + (tid & 192)) * 16;
                __builtin_amdgcn_global_load_lds((const GLOBAL_AS void*)ga, (LDS_AS void*)la, 16, 0, 0);
                __builtin_amdgcn_global_load_lds((const GLOBAL_AS void*)gb, (LDS_AS void*)lb2, 16, 0, 0);
            }
            __syncthreads();
#pragma unroll
            for (int kt = 0; kt < 2; ++kt) {
                bf16x8 af[4], bfr[4];
                const int kq = kt * 4 + quad;
#pragma unroll
                for (int i2 = 0; i2 < 4; ++i2) {
                    int ml = mwb + i2 * 16 + l15;
                    af[i2]  = *(const LDS_AS bf16x8*)(sA + (size_t)(ml * 8 + (kq ^ (ml & 7))) * 16);
                    int nl = nwb + i2 * 16 + l15;
                    bfr[i2] = *(const LDS_AS bf16x8*)(sB + (size_t)(nl * 8 + (kq ^ (nl & 7))) * 16);
                }
#pragma unroll
                for (int i2 = 0; i2 < 4; ++i2)
#pragma unroll
                    for (int j2 = 0; j2 < 4; ++j2)
                        acc[i2][j2] = __builtin_amdgcn_mfma_f32_16x16x32_bf16(af[i2], bfr[j2], acc[i2][j2], 0, 0, 0);
            }
            __syncthreads();
        }

#pragma unroll
        for (int im = 0; im < 4; ++im) {
#pragma unroll
            for (int jn = 0; jn < 4; ++jn) {
                const int rr  = row0 + mwb + im * 16 + quad * 4;
                const int col = col0 + nwb + jn * 16 + l15;
                f32x4 v = acc[im][jn];
                if (col < Cc) {
                    float bi = p.bc[col];
#pragma unroll
                    for (int g = 0; g < 4; ++g)
                        p.out[(size_t)(rr + g) * Cc + col] = v[g] + bi;
                }
            }
        }
    }
}

// ---------------------------------------------------------------------------
// Conversions (unchanged from R3)
// ---------------------------------------------------------------------------
__global__ void cvt_w(const float* __restrict__ a0, const float* __restrict__ a1,
                      const float* __restrict__ a2, const float* __restrict__ a3,
                      bf16_t* __restrict__ o0, bf16_t* __restrict__ o1,
                      bf16_t* __restrict__ o2, bf16_t* __restrict__ o3)
{
    int idx = blockIdx.x * 256 + threadIdx.x;
    int mat = idx >> 20;
    int r   = (idx >> 8) & 4095;
    int k4  = (idx & 255) * 4;
    int n = r >> 2, g = r & 3;
    const float* src = mat == 0 ? a0 : mat == 1 ? a1 : mat == 2 ? a2 : a3;
    bf16_t*      dst = mat == 0 ? o0 : mat == 1 ? o1 : mat == 2 ? o2 : o3;
    f32x4 v = *(const f32x4*)(src + (size_t)(g * Hh + n) * Kk + k4);
    bf16x4 o;
    o[0] = (bf16_t)v[0]; o[1] = (bf16_t)v[1]; o[2] = (bf16_t)v[2]; o[3] = (bf16_t)v[3];
    *(bf16x4*)(dst + (size_t)r * Kk + k4) = o;
}

__global__ void cvt_bias(const float* __restrict__ bih_r, const float* __restrict__ bhh_r,
                         const float* __restrict__ bih_u, const float* __restrict__ bhh_u,
                         float* __restrict__ br, float* __restrict__ bu)
{
    int r = blockIdx.x * 256 + threadIdx.x;
    int n = r >> 2, g = r & 3;
    int ir = g * Hh + n;
    br[r] = bih_r[ir] + bhh_r[ir];
    bu[r] = bih_u[ir] + bhh_u[ir];
}

__global__ void cvt_x(const float* __restrict__ src, bf16_t* __restrict__ dst)
{
    int idx = blockIdx.x * 256 + threadIdx.x;
    int f4  = (idx & 255) * 4;
    int row = idx >> 8;
    int s = row % 14, b = row / 14;
    f32x4 v = *(const f32x4*)(src + (size_t)row * Kk + f4);
    bf16x4 o;
    o[0] = (bf16_t)v[0]; o[1] = (bf16_t)v[1]; o[2] = (bf16_t)v[2]; o[3] = (bf16_t)v[3];
    *(bf16x4*)(dst + (size_t)(s * 256 + b) * Kk + f4) = o;
}

__global__ void cast_f32_bf16(const float* __restrict__ src, bf16_t* __restrict__ dst, int n4)
{
    int i = blockIdx.x * 256 + threadIdx.x;
    if (i < n4) {
        f32x4 v = *(const f32x4*)(src + (size_t)i * 4);
        bf16x4 o;
        o[0] = (bf16_t)v[0]; o[1] = (bf16_t)v[1]; o[2] = (bf16_t)v[2]; o[3] = (bf16_t)v[3];
        *(bf16x4*)(dst + (size_t)i * 4) = o;
    }
}

// ---------------------------------------------------------------------------
extern "C" void kernel_launch(void* const* d_in, const int* in_sizes, int n_in,
                              void* d_out, int out_size, void* d_ws, size_t ws_size,
                              hipStream_t stream)
{
    const float* x_in  = (const float*)d_in[0];
    const float* Wih_r = (const float*)d_in[1];
    const float* Whh_r = (const float*)d_in[2];
    const float* bih_r = (const float*)d_in[3];
    const float* bhh_r = (const float*)d_in[4];
    const float* Wih_u = (const float*)d_in[5];
    const float* Whh_u = (const float*)d_in[6];
    const float* bih_u = (const float*)d_in[7];
    const float* bhh_u = (const float*)d_in[8];
    const float* Wc    = (const float*)d_in[9];
    const float* bc    = (const float*)d_in[10];
    float* out = (float*)d_out;

    char* ws = (char*)d_ws;
    size_t off = 0;
    auto alloc = [&](size_t bytes) -> char* {
        char* p = ws + off;
        off += (bytes + 255) & ~(size_t)255;
        return p;
    };

    bf16_t*   w_ih2 = (bf16_t*)alloc((size_t)8192 * Kk * 2);   // [roll | unroll]
    bf16_t*   w_hhr = (bf16_t*)alloc((size_t)4096 * Kk * 2);
    bf16_t*   w_hhu = (bf16_t*)alloc((size_t)4096 * Kk * 2);
    bf16_t*   wc_b  = (bf16_t*)alloc((size_t)Cc * Kk * 2);
    bf16_t*   x_b   = (bf16_t*)alloc((size_t)NXc * Kk * 2);
    float*    bias2 = (float*)alloc(8192 * 4);
    bf16_t*   XG2   = (bf16_t*)alloc((size_t)2048 * NXc * 4 * 2);
    bf16_t*   hbuf  = (bf16_t*)alloc((size_t)268 * 131072 * 2); // 70.3 MB
    fp16_t*   c0b   = (fp16_t*)alloc((size_t)NXc * Kk * 2);
    fp16_t*   c1b   = (fp16_t*)alloc((size_t)NXc * Kk * 2);
    unsigned* cnt   = (unsigned*)alloc(16 * 28 * 4);

    // zero h[0] (initial states, also fp16-zero source for c at k=1) + counters
    hipMemsetAsync(hbuf, 0, (size_t)2 * 131072 * 2, stream);
    hipMemsetAsync(cnt, 0, 16 * 28 * 4, stream);

    // conversions
    cvt_w<<<16384, 256, 0, stream>>>(Wih_r, Whh_r, Wih_u, Whh_u,
                                     w_ih2, w_hhr, w_ih2 + (size_t)4096 * Kk, w_hhu);
    cvt_bias<<<16, 256, 0, stream>>>(bih_r, bhh_r, bih_u, bhh_u, bias2, bias2 + 4096);
    cvt_x<<<3584, 256, 0, stream>>>(x_in, x_b);
    cast_f32_bf16<<<(Cc * Kk / 4 + 255) / 256, 256, 0, stream>>>(Wc, wc_b, Cc * Kk / 4);

    // merged input-projection GEMM -> XG2 (roll n 0..1023 | unroll n 1024..2047)
    gemm_xg<<<1792, 256, 0, stream>>>(w_ih2, x_b, 16, 14, 2, 28, bias2, XG2);

    // persistent dataflow kernel: 16 recurrent steps + classifier
    PArgs p;
    p.w_hhu = w_hhu;
    p.w_hhr = w_hhr;
    p.xg_u  = XG2 + (size_t)1024 * NXc * 4;
    p.xg_r  = XG2;
    p.wc    = wc_b;
    p.hbuf  = hbuf;
    p.c0    = c0b;
    p.c1    = c1b;
    p.cnt   = cnt;
    p.bc    = bc;
    p.out   = out;
    lstm_persist<<<512, 256, 0, stream>>>(p);
}